// Round 5
// baseline (386.610 us; speedup 1.0000x reference)
//
#include <hip/hip_runtime.h>

#define NFEAT 2048
#define BATCH 16384

typedef float v4f __attribute__((ext_vector_type(4)));  // clang-native for nt-store

// NO LDS, NO BARRIER. Evidence: four LDS-staged variants (serial, deep-MLP,
// LDS-passthrough, pinned-loads) all land 137-152 us with nothing saturated
// (HBM 30%, VALU 2%, LDS ~0) -> the stage+vmcnt(0)+s_barrier convoy is the
// structure cost. SWAP_PROB=0.1: only ~10% of lanes gather, and they gather
// from the same 8KB row this block just streamed (L1/L2-resident). So:
// pass-through from registers, swapped lanes do an exec-masked GLOBAL gather,
// output via nontemporal store (never re-read; keep L2/L3 for inputs).
__global__ __launch_bounds__(256) void swap_corrupt_kernel(
    const float* __restrict__ x,
    const int*   __restrict__ mask,
    const int*   __restrict__ perm,
    float*       __restrict__ out)
{
    const int r = blockIdx.x;
    const int t = threadIdx.x;
    const size_t base = (size_t)r * NFEAT;

    const float4* __restrict__ x4 = (const float4*)(x + base);
    const int4*   __restrict__ m4 = (const int4*)(mask + base);
    const int4*   __restrict__ p4 = (const int4*)(perm + base);
    const float*  __restrict__ xr = x + base;   // gather source: original row

    // ---- coalesced streaming loads (6 x b128 per thread) ----
    float4 a  = x4[t];
    float4 b  = x4[t + 256];
    int4   m0 = m4[t];
    int4   m1 = m4[t + 256];
    int4   p0 = p4[t];
    int4   p1 = p4[t + 256];

    v4f* __restrict__ o4 = (v4f*)(out + base);

    // ---- select; swapped lanes (~10%) gather from global (cache-hot row) ----
    {
        v4f o;
        o.x = m0.x ? xr[p0.x] : a.x;
        o.y = m0.y ? xr[p0.y] : a.y;
        o.z = m0.z ? xr[p0.z] : a.z;
        o.w = m0.w ? xr[p0.w] : a.w;
        __builtin_nontemporal_store(o, &o4[t]);
    }
    {
        v4f o;
        o.x = m1.x ? xr[p1.x] : b.x;
        o.y = m1.y ? xr[p1.y] : b.y;
        o.z = m1.z ? xr[p1.z] : b.z;
        o.w = m1.w ? xr[p1.w] : b.w;
        __builtin_nontemporal_store(o, &o4[t + 256]);
    }
}

extern "C" void kernel_launch(void* const* d_in, const int* in_sizes, int n_in,
                              void* d_out, int out_size, void* d_ws, size_t ws_size,
                              hipStream_t stream) {
    const float* x    = (const float*)d_in[0];
    const int*   mask = (const int*)d_in[1];
    const int*   perm = (const int*)d_in[2];
    float*       out  = (float*)d_out;

    swap_corrupt_kernel<<<dim3(BATCH), dim3(256), 0, stream>>>(x, mask, perm, out);
}